// Round 5
// baseline (3101.258 us; speedup 1.0000x reference)
//
#include <hip/hip_runtime.h>
#include <math.h>

// ---------------------------------------------------------------------------
// AdvancedMixConsole: 64 tracks x 131072 samples.
//   gain -> 6 biquads (chunk-parallel linear recurrence, 12-dim state)
//        -> compressor: parallel static gain; serial smoother as 8-sample
//           composed max-affine chain (9 slopes aa^j ar^(8-j)), one wave per
//           track, UNIFORM-ADDRESS loads (no readlane); intermediate samples
//           reconstructed in parallel from window-boundary q.
//        -> pan/mix (parallel, two-stage).
// ---------------------------------------------------------------------------

#define S_LEN 131072
#define NTR   64
#define CCH   256          // chunks
#define LCH   512          // samples per chunk
#define NSTEP 16384        // 8-sample windows per track
#define WPC   64           // windows per chunk

typedef float v2f __attribute__((ext_vector_type(2)));

// ws offsets in floats (total ~106.5 MB)
#define OFF_Y    0ull              // [131072][64]      EQ output y, sample-major
#define OFF_CI   8388608ull        // [64][NSTEP][16]   composed intercepts I[0..8], 64B records
#define OFF_TV   8388608ull        // [131072][64]      tv = y*gain (ALIASES CI; used after k_smooth)
#define OFF_QB   25165824ull       // [NSTEP][64]       boundary q after each window
#define OFF_W    26214400ull       // [64][2]           cos/sin pan weights
#define OFF_COEF 26214528ull       // [64][32]          biquad coeffs
#define OFF_COMP 26216576ull       // [64][32]          compressor consts + 9 slopes
#define OFF_A    26218624ull       // [64][144]         cascade transition matrix
#define OFF_M    26227840ull       // [64][144]         A^LCH
#define OFF_F    26237056ull       // [64][CCH][12]     zero-init chunk finals
#define OFF_Z    26433664ull       // [64][CCH][12]     chunk init states

// ---------------------------------------------------------------------------
__global__ __launch_bounds__(64) void k_setup(const float* __restrict__ mp,
                                              float* __restrict__ ws) {
  int n = threadIdx.x;
  if (n >= NTR) return;
  const float* p = mp + n * 26;
  auto dn = [&](int i, double lo, double hi) { return (double)p[i] * (hi - lo) + lo; };

  double gain_db = dn(0, -24.0, 24.0);
  double glin = pow(10.0, gain_db / 20.0);
  const double nyq = 21050.0;  // 44100//2 - 1000

  double fg[6] = {dn(1,-24,24), dn(4,-24,24), dn(7,-24,24), dn(10,-24,24), dn(13,-24,24), dn(16,-24,24)};
  double ff[6] = {dn(2,20,2000), dn(5,80,2000), dn(8,2000,8000), dn(11,8000,12000), dn(14,12000,nyq), dn(17,6000,nyq)};
  double fq[6] = {dn(3,0.1,5), dn(6,0.1,5), dn(9,0.1,5), dn(12,0.1,5), dn(15,0.1,5), dn(18,0.1,5)};

  double B0[6], B1[6], B2[6], A1[6], A2[6];
  for (int k = 0; k < 6; k++) {
    double A  = pow(10.0, fg[k] / 40.0);
    double w0 = 2.0 * M_PI * ff[k] / 44100.0;
    double cw = cos(w0), sw = sin(w0);
    double al = sw / (2.0 * fq[k]);
    double sA = sqrt(A);
    double b0, b1, b2, a0, a1, a2;
    if (k == 0) {           // low shelf
      b0 = A*((A+1)-(A-1)*cw + 2*sA*al);
      b1 = 2*A*((A-1)-(A+1)*cw);
      b2 = A*((A+1)-(A-1)*cw - 2*sA*al);
      a0 = (A+1)+(A-1)*cw + 2*sA*al;
      a1 = -2*((A-1)+(A+1)*cw);
      a2 = (A+1)+(A-1)*cw - 2*sA*al;
    } else if (k == 5) {    // high shelf
      b0 = A*((A+1)+(A-1)*cw + 2*sA*al);
      b1 = -2*A*((A-1)+(A+1)*cw);
      b2 = A*((A+1)+(A-1)*cw - 2*sA*al);
      a0 = (A+1)-(A-1)*cw + 2*sA*al;
      a1 = 2*((A-1)-(A+1)*cw);
      a2 = (A+1)-(A-1)*cw - 2*sA*al;
    } else {                // peak
      b0 = 1 + al*A; b1 = -2*cw; b2 = 1 - al*A;
      a0 = 1 + al/A; a1 = -2*cw; a2 = 1 - al/A;
    }
    B0[k] = b0/a0; B1[k] = b1/a0; B2[k] = b2/a0; A1[k] = a1/a0; A2[k] = a2/a0;
  }
  // fold input gain into stage-0 numerator
  B0[0] *= glin; B1[0] *= glin; B2[0] *= glin;

  float* cf = ws + OFF_COEF + n * 32;
  for (int k = 0; k < 6; k++) {
    cf[k*5+0] = (float)B0[k]; cf[k*5+1] = (float)B1[k]; cf[k*5+2] = (float)B2[k];
    cf[k*5+3] = (float)A1[k]; cf[k*5+4] = (float)A2[k];
  }

  // compressor + pan constants
  double T = dn(19,-60,0), R = dn(20,1,10), atk = dn(21,1,1000), rel = dn(22,1,1000);
  double Kn = dn(23,3,24), mk = dn(24,0,24);
  double a_a = exp(-1.0 / (44100.0 * atk * 0.001));
  double a_r = exp(-1.0 / (44100.0 * rel * 0.001));
  double s   = (a_a < a_r) ? 1.0 : -1.0;     // q = s*p makes the recurrence pure-max
  double kca = s * (1.0 - a_a), kcr = s * (1.0 - a_r);
  double invR = 1.0 / R;
  const double K10 = 0.16609640474436813;    // log2(10)/20
  double theta = (double)p[25] * (M_PI / 2.0);

  float* cm = ws + OFF_COMP + n * 32;
  cm[0] = (float)a_a;  cm[1] = (float)a_r;  cm[2] = (float)kca; cm[3] = (float)kcr;
  cm[4] = (float)T;    cm[5] = (float)(Kn * 0.5);
  cm[6] = (float)(1.0 - invR);
  cm[7] = (float)((1.0 - invR) / (2.0 * Kn));
  cm[8] = (float)(mk * K10);   cm[9] = (float)(s * K10);
  cm[10] = (float)cos(theta);  cm[11] = (float)sin(theta);
  // 9 composed slopes aa^j * ar^(8-j), j = 0..8 (double-precision products)
  for (int j = 0; j <= 8; j++)
    cm[16+j] = (float)(pow(a_a, (double)j) * pow(a_r, (double)(8-j)));

  float* wp = ws + OFF_W + n*2;
  wp[0] = (float)cos(theta); wp[1] = (float)sin(theta);

  // homogeneous (x=0) cascade transition matrix, state = [s1_1,s2_1,...,s1_6,s2_6]
  double Am[12][12], yv[12], ny[12];
  for (int r = 0; r < 12; r++) { yv[r] = 0; for (int c = 0; c < 12; c++) Am[r][c] = 0; }
  for (int k = 0; k < 6; k++) {
    for (int c = 0; c < 12; c++) ny[c] = B0[k] * yv[c];
    ny[2*k] += 1.0;                                  // y_k = b0*y_{k-1} + s1_k
    for (int c = 0; c < 12; c++) Am[2*k][c]   = B1[k]*yv[c] - A1[k]*ny[c];
    Am[2*k][2*k+1] += 1.0;                           // + s2_k
    for (int c = 0; c < 12; c++) Am[2*k+1][c] = B2[k]*yv[c] - A2[k]*ny[c];
    for (int c = 0; c < 12; c++) yv[c] = ny[c];
  }
  float* Aw = ws + OFF_A + n * 144;
  for (int r = 0; r < 12; r++)
    for (int c = 0; c < 12; c++) Aw[r*12+c] = (float)Am[r][c];
}

// ---------------------------------------------------------------------------
__global__ __launch_bounds__(192) void k_matpow(float* __restrict__ ws) {
  __shared__ float As[144];
  int n = blockIdx.x, t = threadIdx.x;
  int r = t / 12, c = t % 12;
  if (t < 144) As[t] = ws[OFF_A + (size_t)n*144 + t];
  __syncthreads();
  for (int it = 0; it < 9; ++it) {   // A^(2^9) = A^LCH (LCH=512)
    float acc = 0.f;
    if (t < 144) {
      #pragma unroll
      for (int k = 0; k < 12; k++) acc += As[r*12+k] * As[k*12+c];
    }
    __syncthreads();
    if (t < 144) As[t] = acc;
    __syncthreads();
  }
  if (t < 144) ws[OFF_M + (size_t)n*144 + t] = As[t];
}

// ---------------------------------------------------------------------------
__device__ __forceinline__ void load_coefs(const float* cf, float* b0, v2f* bb, v2f* naa) {
  #pragma unroll
  for (int k = 0; k < 6; k++) {
    b0[k]  = cf[k*5+0];
    bb[k]  = (v2f){cf[k*5+1], cf[k*5+2]};
    naa[k] = (v2f){-cf[k*5+3], -cf[k*5+4]};
  }
}

__device__ __forceinline__ float cascade_step(float x, float* b0, v2f* bb, v2f* naa, v2f* st) {
  #pragma unroll
  for (int k = 0; k < 6; k++) {
    float y  = fmaf(b0[k], x, st[k].x);
    v2f upd  = __builtin_elementwise_fma(bb[k], (v2f){x, x}, (v2f){st[k].y, 0.f});
    st[k]    = __builtin_elementwise_fma(naa[k], (v2f){y, y}, upd);
    x = y;
  }
  return x;
}

// phase 1: zero-init chunk finals
__global__ __launch_bounds__(64) void k_phase1(const float* __restrict__ tracks,
                                               float* __restrict__ ws) {
  int j = blockIdx.x, n = threadIdx.x;
  float b0[6]; v2f bb[6], naa[6];
  load_coefs(ws + OFF_COEF + n*32, b0, bb, naa);
  v2f st[6];
  #pragma unroll
  for (int k = 0; k < 6; k++) st[k] = (v2f){0.f, 0.f};
  const float4* xp = (const float4*)(tracks + (size_t)n*S_LEN + (size_t)j*LCH);
  for (int i4 = 0; i4 < LCH/4; ++i4) {
    float4 xq = xp[i4];
    float xs[4] = {xq.x, xq.y, xq.z, xq.w};
    #pragma unroll
    for (int u = 0; u < 4; u++) (void)cascade_step(xs[u], b0, bb, naa, st);
  }
  float* f = ws + OFF_F + (size_t)n*(CCH*12) + (size_t)j*12;
  #pragma unroll
  for (int k = 0; k < 6; k++) { f[2*k] = st[k].x; f[2*k+1] = st[k].y; }
}

// serial scan of chunk-boundary states: z_{j+1} = M z_j + f_j
__global__ __launch_bounds__(64) void k_scanz(float* __restrict__ ws) {
  int n = threadIdx.x;
  float M[144];
  #pragma unroll
  for (int i = 0; i < 144; i++) M[i] = ws[OFF_M + (size_t)n*144 + i];
  float z[12];
  #pragma unroll
  for (int r = 0; r < 12; r++) z[r] = 0.f;
  const float* fb = ws + OFF_F + (size_t)n*(CCH*12);
  float*       zb = ws + OFF_Z + (size_t)n*(CCH*12);
  for (int j = 0; j < CCH; j++) {
    #pragma unroll
    for (int r = 0; r < 12; r++) zb[j*12+r] = z[r];
    float nz[12];
    #pragma unroll
    for (int r = 0; r < 12; r++) {
      float acc = fb[j*12+r];
      #pragma unroll
      for (int c = 0; c < 12; c++) acc = fmaf(M[r*12+c], z[c], acc);
      nz[r] = acc;
    }
    #pragma unroll
    for (int r = 0; r < 12; r++) z[r] = nz[r];
  }
}

// phase 3: correct-init EQ; per-sample static gain; per-8-sample-window
// composed max-affine intercepts I[0..8], written as 64B records
// [track][step][16] so k_smooth streams them with uniform loads.
__global__ __launch_bounds__(64) void k_phase3(const float* __restrict__ tracks,
                                               float* __restrict__ ws) {
  int j = blockIdx.x, n = threadIdx.x;
  float b0[6]; v2f bb[6], naa[6];
  load_coefs(ws + OFF_COEF + n*32, b0, bb, naa);
  const float* cm = ws + OFF_COMP + n*32;
  float a_a = cm[0], a_r = cm[1], kca = cm[2], kcr = cm[3];
  float T = cm[4], hK = cm[5], cg1 = cm[6], cg2 = cm[7];
  v2f st[6];
  const float* zp = ws + OFF_Z + (size_t)n*(CCH*12) + (size_t)j*12;
  #pragma unroll
  for (int k = 0; k < 6; k++) st[k] = (v2f){zp[2*k], zp[2*k+1]};

  const float4* xp = (const float4*)(tracks + (size_t)n*S_LEN + (size_t)j*LCH);
  float* yb = ws + OFF_Y + (size_t)j*LCH*64 + n;                    // [sample][track]
  float* cw = ws + OFF_CI + ((size_t)n*NSTEP + (size_t)j*WPC)*16;   // [track][step][16]

  for (int w = 0; w < WPC; ++w) {
    float I[9];
    I[0] = 0.f;
    #pragma unroll
    for (int jj = 1; jj < 9; ++jj) I[jj] = -1e30f;
    #pragma unroll
    for (int i4 = 0; i4 < 2; ++i4) {
      float4 xq = xp[w*2 + i4];
      float xs[4] = {xq.x, xq.y, xq.z, xq.w};
      #pragma unroll
      for (int u = 0; u < 4; ++u) {
        const int i = i4*4 + u;
        float y = cascade_step(xs[u], b0, bb, naa, st);
        yb[(w*8 + i)*64] = y;
        float v   = fabsf(y) + 1e-8f;
        float xdb = 6.020599913279624f * __log2f(v);
        float d   = xdb - T;
        float dk  = d + hK;
        float gg  = (d > hK) ? (cg1*d) : (cg2*dk*dk);
        gg = (d < -hK) ? 0.f : gg;
        float ca = kca*gg, cr = kcr*gg;
        // compose one sample into the window map (descending j, in place)
        #pragma unroll
        for (int jj = 8; jj >= 0; --jj) {
          if (jj <= i+1) {
            float up = (jj > 0) ? fmaf(a_a, I[jj-1], ca) : -1e30f;
            I[jj] = fmaxf(up, fmaf(a_r, I[jj], cr));
          }
        }
      }
    }
    float4* cq = (float4*)(cw + (size_t)w*16);
    cq[0] = make_float4(I[0], I[1], I[2], I[3]);
    cq[1] = make_float4(I[4], I[5], I[6], I[7]);
    cq[2] = make_float4(I[8], 0.f, 0.f, 0.f);
    cq[3] = make_float4(0.f, 0.f, 0.f, 0.f);   // complete the 64B line
  }
}

// ---------------------------------------------------------------------------
// serial max-affine smoother: one wave per track; one 9-term step per
// 8 samples. ALL lanes load the SAME step record (uniform address -> one
// 64B line request, data lands in VGPRs — no readlane, no SGPR hazards).
// 16-deep register ring hides memory latency. Lane (st&63) captures q.
__global__ __launch_bounds__(64) void k_smooth(const float4* __restrict__ cp,
                                               const float* __restrict__ cmv,
                                               float* __restrict__ qb) {
  const int n = blockIdx.x, l = threadIdx.x;
  const float* cm = cmv + n*32;
  float S[9];
  #pragma unroll
  for (int j = 0; j < 9; ++j) S[j] = cm[16+j];

  const float4* base = cp + (size_t)n * NSTEP * 4;   // 4 float4 per step
  float4 r0[16], r1[16], r2[16];
  #pragma unroll
  for (int d = 0; d < 16; ++d) {
    r0[d] = base[d*4 + 0];
    r1[d] = base[d*4 + 1];
    r2[d] = base[d*4 + 2];
  }

  float q = 0.f, qs = 0.f;
  for (int g = 0; g < NSTEP/16; ++g) {
    const bool pf = (g + 1 < NSTEP/16);
    #pragma unroll
    for (int u = 0; u < 16; ++u) {
      const int st = g*16 + u;
      float4 c0 = r0[u], c1 = r1[u], c2 = r2[u];
      if (pf) {
        const float4* nx = base + (size_t)(st + 16)*4;
        r0[u] = nx[0]; r1[u] = nx[1]; r2[u] = nx[2];
      }
      float t0 = fmaf(S[0], q, c0.x);
      float t1 = fmaf(S[1], q, c0.y);
      float t2 = fmaf(S[2], q, c0.z);
      float t3 = fmaf(S[3], q, c0.w);
      float t4 = fmaf(S[4], q, c1.x);
      float t5 = fmaf(S[5], q, c1.y);
      float t6 = fmaf(S[6], q, c1.z);
      float t7 = fmaf(S[7], q, c1.w);
      float t8 = fmaf(S[8], q, c2.x);
      float m0 = fmaxf(fmaxf(t0, t1), t2);     // v_max3
      float m1 = fmaxf(fmaxf(t3, t4), t5);
      float m2 = fmaxf(fmaxf(t6, t7), t8);
      q = fmaxf(fmaxf(m0, m1), m2);
      qs = (l == (st & 63)) ? q : qs;           // lane st&63 captures window st
    }
    if ((g & 3) == 3) {                         // every 64 windows: coalesced-ish store
      const int h = g >> 2;
      qb[(size_t)(h*64 + l)*64 + n] = qs;       // [window][track]
    }
  }
}

// tv = y * 10^((mk - p)/20): exact 8-step reconstruction from boundary q.
// lanes = tracks -> fully coalesced y/tv rows.
__global__ __launch_bounds__(256) void k_mix1(float* __restrict__ ws) {
  const int n  = threadIdx.x & 63;
  const int kk = blockIdx.x*4 + (threadIdx.x >> 6);
  const float* cm = ws + OFF_COMP + n*32;
  const float aa = cm[0], ar = cm[1], kca = cm[2], kcr = cm[3];
  const float T = cm[4], hK = cm[5], cg1 = cm[6], cg2 = cm[7];
  const float mkK = cm[8], sK = cm[9];
  const float* __restrict__ yb  = ws + OFF_Y;
  float* __restrict__       tvb = ws + OFF_TV;
  float q = (kk > 0) ? ws[OFF_QB + (size_t)(kk-1)*64 + n] : 0.f;
  #pragma unroll
  for (int i = 0; i < 8; ++i) {
    float y = yb[(size_t)(kk*8 + i)*64 + n];
    float v   = fabsf(y) + 1e-8f;
    float xdb = 6.020599913279624f * __log2f(v);
    float d   = xdb - T;
    float dk  = d + hK;
    float gg  = (d > hK) ? (cg1*d) : (cg2*dk*dk);
    gg = (d < -hK) ? 0.f : gg;
    q = fmaxf(fmaf(aa, q, kca*gg), fmaf(ar, q, kcr*gg));
    float sc = exp2f(fmaf(-sK, q, mkK));
    tvb[(size_t)(kk*8 + i)*64 + n] = y * sc;
  }
}

// 16-track pan reduction -> out[b][2][S]
__global__ __launch_bounds__(256) void k_mix2(const float* __restrict__ ws,
                                              float* __restrict__ out) {
  const int b = threadIdx.x & 3;
  const int s = blockIdx.x*64 + (threadIdx.x >> 2);
  const float* __restrict__ tvb = ws + OFF_TV;
  const float2* __restrict__ wp = (const float2*)(ws + OFF_W);
  float accL = 0.f, accR = 0.f;
  const int n0 = b*16;
  #pragma unroll
  for (int t = 0; t < 16; ++t) {
    float tv = tvb[(size_t)s*64 + n0 + t];
    float2 w2 = wp[n0 + t];
    accL = fmaf(w2.x, tv, accL);
    accR = fmaf(w2.y, tv, accR);
  }
  out[(size_t)(b*2 + 0)*S_LEN + s] = accL;
  out[(size_t)(b*2 + 1)*S_LEN + s] = accR;
}

// ---------------------------------------------------------------------------
extern "C" void kernel_launch(void* const* d_in, const int* in_sizes, int n_in,
                              void* d_out, int out_size, void* d_ws, size_t ws_size,
                              hipStream_t stream) {
  const float* tracks = (const float*)d_in[0];
  const float* mp     = (const float*)d_in[1];
  float* ws  = (float*)d_ws;
  float* out = (float*)d_out;

  hipLaunchKernelGGL(k_setup,  dim3(1),    dim3(64),  0, stream, mp, ws);
  hipLaunchKernelGGL(k_matpow, dim3(64),   dim3(192), 0, stream, ws);
  hipLaunchKernelGGL(k_phase1, dim3(CCH),  dim3(64),  0, stream, tracks, ws);
  hipLaunchKernelGGL(k_scanz,  dim3(1),    dim3(64),  0, stream, ws);
  hipLaunchKernelGGL(k_phase3, dim3(CCH),  dim3(64),  0, stream, tracks, ws);
  hipLaunchKernelGGL(k_smooth, dim3(NTR),  dim3(64),  0, stream,
                     (const float4*)(ws + OFF_CI), ws + OFF_COMP, ws + OFF_QB);
  hipLaunchKernelGGL(k_mix1,   dim3(NSTEP/4),  dim3(256), 0, stream, ws);
  hipLaunchKernelGGL(k_mix2,   dim3(S_LEN/64), dim3(256), 0, stream, ws, out);
}

// Round 6
// 1463.876 us; speedup vs baseline: 2.1185x; 2.1185x over previous
//
#include <hip/hip_runtime.h>
#include <math.h>

// ---------------------------------------------------------------------------
// AdvancedMixConsole: 64 tracks x 131072 samples.
//   gain -> 6 biquads (chunk-parallel linear recurrence, 12-dim state)
//        -> compressor: parallel static gain; serial smoother as 8-sample
//           composed max-affine chain (9 slopes aa^j ar^(8-j)); one block per
//           track: wave0 = chain (uniform ds_read, named-reg depth-8 pipe),
//           waves1-3 = global->LDS producers (double-buffered chunks).
//        -> pan/mix (parallel, two-stage).
// ---------------------------------------------------------------------------

#define S_LEN 131072
#define NTR   64
#define CCH   256          // chunks (biquad phase)
#define LCH   512          // samples per chunk
#define NSTEP 16384        // 8-sample windows per track
#define WPC   64           // windows per biquad chunk
#define SCH   256          // k_smooth steps per LDS chunk
#define NCH   (NSTEP/SCH)  // 64 LDS chunks

typedef float v2f __attribute__((ext_vector_type(2)));

// ws offsets in floats (total ~106.5 MB)
#define OFF_Y    0ull              // [131072][64]      EQ output y, sample-major
#define OFF_CI   8388608ull        // [64][NSTEP][16]   composed intercepts I[0..8], 64B records
#define OFF_TV   8388608ull        // [131072][64]      tv = y*gain (ALIASES CI; used after k_smooth)
#define OFF_QB   25165824ull       // [NSTEP][64]       boundary q after each window
#define OFF_W    26214400ull       // [64][2]           cos/sin pan weights
#define OFF_COEF 26214528ull       // [64][32]          biquad coeffs
#define OFF_COMP 26216576ull       // [64][32]          compressor consts + 9 slopes
#define OFF_A    26218624ull       // [64][144]         cascade transition matrix
#define OFF_M    26227840ull       // [64][144]         A^LCH
#define OFF_F    26237056ull       // [64][CCH][12]     zero-init chunk finals
#define OFF_Z    26433664ull       // [64][CCH][12]     chunk init states

// ---------------------------------------------------------------------------
__global__ __launch_bounds__(64) void k_setup(const float* __restrict__ mp,
                                              float* __restrict__ ws) {
  int n = threadIdx.x;
  if (n >= NTR) return;
  const float* p = mp + n * 26;
  auto dn = [&](int i, double lo, double hi) { return (double)p[i] * (hi - lo) + lo; };

  double gain_db = dn(0, -24.0, 24.0);
  double glin = pow(10.0, gain_db / 20.0);
  const double nyq = 21050.0;  // 44100//2 - 1000

  double fg[6] = {dn(1,-24,24), dn(4,-24,24), dn(7,-24,24), dn(10,-24,24), dn(13,-24,24), dn(16,-24,24)};
  double ff[6] = {dn(2,20,2000), dn(5,80,2000), dn(8,2000,8000), dn(11,8000,12000), dn(14,12000,nyq), dn(17,6000,nyq)};
  double fq[6] = {dn(3,0.1,5), dn(6,0.1,5), dn(9,0.1,5), dn(12,0.1,5), dn(15,0.1,5), dn(18,0.1,5)};

  double B0[6], B1[6], B2[6], A1[6], A2[6];
  for (int k = 0; k < 6; k++) {
    double A  = pow(10.0, fg[k] / 40.0);
    double w0 = 2.0 * M_PI * ff[k] / 44100.0;
    double cw = cos(w0), sw = sin(w0);
    double al = sw / (2.0 * fq[k]);
    double sA = sqrt(A);
    double b0, b1, b2, a0, a1, a2;
    if (k == 0) {           // low shelf
      b0 = A*((A+1)-(A-1)*cw + 2*sA*al);
      b1 = 2*A*((A-1)-(A+1)*cw);
      b2 = A*((A+1)-(A-1)*cw - 2*sA*al);
      a0 = (A+1)+(A-1)*cw + 2*sA*al;
      a1 = -2*((A-1)+(A+1)*cw);
      a2 = (A+1)+(A-1)*cw - 2*sA*al;
    } else if (k == 5) {    // high shelf
      b0 = A*((A+1)+(A-1)*cw + 2*sA*al);
      b1 = -2*A*((A-1)+(A+1)*cw);
      b2 = A*((A+1)+(A-1)*cw - 2*sA*al);
      a0 = (A+1)-(A-1)*cw + 2*sA*al;
      a1 = 2*((A-1)-(A+1)*cw);
      a2 = (A+1)-(A-1)*cw - 2*sA*al;
    } else {                // peak
      b0 = 1 + al*A; b1 = -2*cw; b2 = 1 - al*A;
      a0 = 1 + al/A; a1 = -2*cw; a2 = 1 - al/A;
    }
    B0[k] = b0/a0; B1[k] = b1/a0; B2[k] = b2/a0; A1[k] = a1/a0; A2[k] = a2/a0;
  }
  // fold input gain into stage-0 numerator
  B0[0] *= glin; B1[0] *= glin; B2[0] *= glin;

  float* cf = ws + OFF_COEF + n * 32;
  for (int k = 0; k < 6; k++) {
    cf[k*5+0] = (float)B0[k]; cf[k*5+1] = (float)B1[k]; cf[k*5+2] = (float)B2[k];
    cf[k*5+3] = (float)A1[k]; cf[k*5+4] = (float)A2[k];
  }

  // compressor + pan constants
  double T = dn(19,-60,0), R = dn(20,1,10), atk = dn(21,1,1000), rel = dn(22,1,1000);
  double Kn = dn(23,3,24), mk = dn(24,0,24);
  double a_a = exp(-1.0 / (44100.0 * atk * 0.001));
  double a_r = exp(-1.0 / (44100.0 * rel * 0.001));
  double s   = (a_a < a_r) ? 1.0 : -1.0;     // q = s*p makes the recurrence pure-max
  double kca = s * (1.0 - a_a), kcr = s * (1.0 - a_r);
  double invR = 1.0 / R;
  const double K10 = 0.16609640474436813;    // log2(10)/20
  double theta = (double)p[25] * (M_PI / 2.0);

  float* cm = ws + OFF_COMP + n * 32;
  cm[0] = (float)a_a;  cm[1] = (float)a_r;  cm[2] = (float)kca; cm[3] = (float)kcr;
  cm[4] = (float)T;    cm[5] = (float)(Kn * 0.5);
  cm[6] = (float)(1.0 - invR);
  cm[7] = (float)((1.0 - invR) / (2.0 * Kn));
  cm[8] = (float)(mk * K10);   cm[9] = (float)(s * K10);
  cm[10] = (float)cos(theta);  cm[11] = (float)sin(theta);
  // 9 composed slopes aa^j * ar^(8-j), j = 0..8 (double-precision products)
  for (int j = 0; j <= 8; j++)
    cm[16+j] = (float)(pow(a_a, (double)j) * pow(a_r, (double)(8-j)));

  float* wp = ws + OFF_W + n*2;
  wp[0] = (float)cos(theta); wp[1] = (float)sin(theta);

  // homogeneous (x=0) cascade transition matrix, state = [s1_1,s2_1,...,s1_6,s2_6]
  double Am[12][12], yv[12], ny[12];
  for (int r = 0; r < 12; r++) { yv[r] = 0; for (int c = 0; c < 12; c++) Am[r][c] = 0; }
  for (int k = 0; k < 6; k++) {
    for (int c = 0; c < 12; c++) ny[c] = B0[k] * yv[c];
    ny[2*k] += 1.0;                                  // y_k = b0*y_{k-1} + s1_k
    for (int c = 0; c < 12; c++) Am[2*k][c]   = B1[k]*yv[c] - A1[k]*ny[c];
    Am[2*k][2*k+1] += 1.0;                           // + s2_k
    for (int c = 0; c < 12; c++) Am[2*k+1][c] = B2[k]*yv[c] - A2[k]*ny[c];
    for (int c = 0; c < 12; c++) yv[c] = ny[c];
  }
  float* Aw = ws + OFF_A + n * 144;
  for (int r = 0; r < 12; r++)
    for (int c = 0; c < 12; c++) Aw[r*12+c] = (float)Am[r][c];
}

// ---------------------------------------------------------------------------
__global__ __launch_bounds__(192) void k_matpow(float* __restrict__ ws) {
  __shared__ float As[144];
  int n = blockIdx.x, t = threadIdx.x;
  int r = t / 12, c = t % 12;
  if (t < 144) As[t] = ws[OFF_A + (size_t)n*144 + t];
  __syncthreads();
  for (int it = 0; it < 9; ++it) {   // A^(2^9) = A^LCH (LCH=512)
    float acc = 0.f;
    if (t < 144) {
      #pragma unroll
      for (int k = 0; k < 12; k++) acc += As[r*12+k] * As[k*12+c];
    }
    __syncthreads();
    if (t < 144) As[t] = acc;
    __syncthreads();
  }
  if (t < 144) ws[OFF_M + (size_t)n*144 + t] = As[t];
}

// ---------------------------------------------------------------------------
__device__ __forceinline__ void load_coefs(const float* cf, float* b0, v2f* bb, v2f* naa) {
  #pragma unroll
  for (int k = 0; k < 6; k++) {
    b0[k]  = cf[k*5+0];
    bb[k]  = (v2f){cf[k*5+1], cf[k*5+2]};
    naa[k] = (v2f){-cf[k*5+3], -cf[k*5+4]};
  }
}

__device__ __forceinline__ float cascade_step(float x, float* b0, v2f* bb, v2f* naa, v2f* st) {
  #pragma unroll
  for (int k = 0; k < 6; k++) {
    float y  = fmaf(b0[k], x, st[k].x);
    v2f upd  = __builtin_elementwise_fma(bb[k], (v2f){x, x}, (v2f){st[k].y, 0.f});
    st[k]    = __builtin_elementwise_fma(naa[k], (v2f){y, y}, upd);
    x = y;
  }
  return x;
}

// phase 1: zero-init chunk finals
__global__ __launch_bounds__(64) void k_phase1(const float* __restrict__ tracks,
                                               float* __restrict__ ws) {
  int j = blockIdx.x, n = threadIdx.x;
  float b0[6]; v2f bb[6], naa[6];
  load_coefs(ws + OFF_COEF + n*32, b0, bb, naa);
  v2f st[6];
  #pragma unroll
  for (int k = 0; k < 6; k++) st[k] = (v2f){0.f, 0.f};
  const float4* xp = (const float4*)(tracks + (size_t)n*S_LEN + (size_t)j*LCH);
  for (int i4 = 0; i4 < LCH/4; ++i4) {
    float4 xq = xp[i4];
    float xs[4] = {xq.x, xq.y, xq.z, xq.w};
    #pragma unroll
    for (int u = 0; u < 4; u++) (void)cascade_step(xs[u], b0, bb, naa, st);
  }
  float* f = ws + OFF_F + (size_t)n*(CCH*12) + (size_t)j*12;
  #pragma unroll
  for (int k = 0; k < 6; k++) { f[2*k] = st[k].x; f[2*k+1] = st[k].y; }
}

// serial scan of chunk-boundary states: z_{j+1} = M z_j + f_j
__global__ __launch_bounds__(64) void k_scanz(float* __restrict__ ws) {
  int n = threadIdx.x;
  float M[144];
  #pragma unroll
  for (int i = 0; i < 144; i++) M[i] = ws[OFF_M + (size_t)n*144 + i];
  float z[12];
  #pragma unroll
  for (int r = 0; r < 12; r++) z[r] = 0.f;
  const float* fb = ws + OFF_F + (size_t)n*(CCH*12);
  float*       zb = ws + OFF_Z + (size_t)n*(CCH*12);
  for (int j = 0; j < CCH; j++) {
    #pragma unroll
    for (int r = 0; r < 12; r++) zb[j*12+r] = z[r];
    float nz[12];
    #pragma unroll
    for (int r = 0; r < 12; r++) {
      float acc = fb[j*12+r];
      #pragma unroll
      for (int c = 0; c < 12; c++) acc = fmaf(M[r*12+c], z[c], acc);
      nz[r] = acc;
    }
    #pragma unroll
    for (int r = 0; r < 12; r++) z[r] = nz[r];
  }
}

// phase 3: correct-init EQ; per-sample static gain; per-8-sample-window
// composed max-affine intercepts I[0..8], written as 64B records
// [track][step][16] so k_smooth streams them with uniform loads.
__global__ __launch_bounds__(64) void k_phase3(const float* __restrict__ tracks,
                                               float* __restrict__ ws) {
  int j = blockIdx.x, n = threadIdx.x;
  float b0[6]; v2f bb[6], naa[6];
  load_coefs(ws + OFF_COEF + n*32, b0, bb, naa);
  const float* cm = ws + OFF_COMP + n*32;
  float a_a = cm[0], a_r = cm[1], kca = cm[2], kcr = cm[3];
  float T = cm[4], hK = cm[5], cg1 = cm[6], cg2 = cm[7];
  v2f st[6];
  const float* zp = ws + OFF_Z + (size_t)n*(CCH*12) + (size_t)j*12;
  #pragma unroll
  for (int k = 0; k < 6; k++) st[k] = (v2f){zp[2*k], zp[2*k+1]};

  const float4* xp = (const float4*)(tracks + (size_t)n*S_LEN + (size_t)j*LCH);
  float* yb = ws + OFF_Y + (size_t)j*LCH*64 + n;                    // [sample][track]
  float* cw = ws + OFF_CI + ((size_t)n*NSTEP + (size_t)j*WPC)*16;   // [track][step][16]

  for (int w = 0; w < WPC; ++w) {
    float I[9];
    I[0] = 0.f;
    #pragma unroll
    for (int jj = 1; jj < 9; ++jj) I[jj] = -1e30f;
    #pragma unroll
    for (int i4 = 0; i4 < 2; ++i4) {
      float4 xq = xp[w*2 + i4];
      float xs[4] = {xq.x, xq.y, xq.z, xq.w};
      #pragma unroll
      for (int u = 0; u < 4; ++u) {
        const int i = i4*4 + u;
        float y = cascade_step(xs[u], b0, bb, naa, st);
        yb[(w*8 + i)*64] = y;
        float v   = fabsf(y) + 1e-8f;
        float xdb = 6.020599913279624f * __log2f(v);
        float d   = xdb - T;
        float dk  = d + hK;
        float gg  = (d > hK) ? (cg1*d) : (cg2*dk*dk);
        gg = (d < -hK) ? 0.f : gg;
        float ca = kca*gg, cr = kcr*gg;
        // compose one sample into the window map (descending j, in place)
        #pragma unroll
        for (int jj = 8; jj >= 0; --jj) {
          if (jj <= i+1) {
            float up = (jj > 0) ? fmaf(a_a, I[jj-1], ca) : -1e30f;
            I[jj] = fmaxf(up, fmaf(a_r, I[jj], cr));
          }
        }
      }
    }
    float4* cq = (float4*)(cw + (size_t)w*16);
    cq[0] = make_float4(I[0], I[1], I[2], I[3]);
    cq[1] = make_float4(I[4], I[5], I[6], I[7]);
    cq[2] = make_float4(I[8], 0.f, 0.f, 0.f);
    cq[3] = make_float4(0.f, 0.f, 0.f, 0.f);   // complete the 64B line
  }
}

// ---------------------------------------------------------------------------
// serial max-affine smoother. One 256-thread block per track:
//   wave 0  = chain consumer (uniform-address ds_read_b128 broadcast,
//             depth-8 pipeline of NAMED float4 locals — no arrays/scratch)
//   waves 1-3 = producers: stream CI global->LDS, double-buffered 16KB chunks.
#define SM_STEP(Ra, Rb, Rc, SL)                                              \
  {                                                                          \
    float t0 = fmaf(S0, q, Ra.x), t1 = fmaf(S1, q, Ra.y);                    \
    float t2 = fmaf(S2, q, Ra.z), t3 = fmaf(S3, q, Ra.w);                    \
    float t4 = fmaf(S4, q, Rb.x), t5 = fmaf(S5, q, Rb.y);                    \
    float t6 = fmaf(S6, q, Rb.z), t7 = fmaf(S7, q, Rb.w);                    \
    float t8 = fmaf(S8, q, Rc.x);                                            \
    float m0 = fmaxf(fmaxf(t0, t1), t2);                                     \
    float m1 = fmaxf(fmaxf(t3, t4), t5);                                     \
    float m2 = fmaxf(fmaxf(t6, t7), t8);                                     \
    q = fmaxf(fmaxf(m0, m1), m2);                                            \
    qs = (l == ((u + SL) & 63)) ? q : qs;                                    \
    if (u + SL + 8 < SCH) {                                                  \
      Ra = Lb[(u + SL + 8)*4 + 0];                                           \
      Rb = Lb[(u + SL + 8)*4 + 1];                                           \
      Rc = Lb[(u + SL + 8)*4 + 2];                                           \
    }                                                                        \
  }

__global__ __launch_bounds__(256) void k_smooth(const float4* __restrict__ cp,
                                                const float* __restrict__ cmv,
                                                float* __restrict__ qb) {
  __shared__ float4 buf[2][SCH*4];          // 2 x 16KB
  const int n = blockIdx.x;
  const int tid = threadIdx.x;
  const int wave = tid >> 6, l = tid & 63;
  const float4* __restrict__ base = cp + (size_t)n * NSTEP * 4;

  // preload chunk 0 (all threads)
  for (int i = tid; i < SCH*4; i += 256) buf[0][i] = base[i];
  __syncthreads();

  const float* cm = cmv + n*32;
  const float S0 = cm[16], S1 = cm[17], S2 = cm[18], S3 = cm[19], S4 = cm[20];
  const float S5 = cm[21], S6 = cm[22], S7 = cm[23], S8 = cm[24];

  float q = 0.f, qs = 0.f;
  for (int c = 0; c < NCH; ++c) {
    if (wave != 0) {
      if (c + 1 < NCH) {
        const float4* src = base + (size_t)(c+1)*SCH*4;
        float4* dst = &buf[(c+1) & 1][0];
        for (int i = tid - 64; i < SCH*4; i += 192) dst[i] = src[i];
      }
    } else {
      const float4* Lb = &buf[c & 1][0];
      // prologue: steps 0..7 of this chunk into named regs
      float4 A0 = Lb[0],  A1 = Lb[1],  A2 = Lb[2];
      float4 B0 = Lb[4],  B1 = Lb[5],  B2 = Lb[6];
      float4 C0 = Lb[8],  C1 = Lb[9],  C2 = Lb[10];
      float4 D0 = Lb[12], D1 = Lb[13], D2 = Lb[14];
      float4 E0 = Lb[16], E1 = Lb[17], E2 = Lb[18];
      float4 F0 = Lb[20], F1 = Lb[21], F2 = Lb[22];
      float4 G0 = Lb[24], G1 = Lb[25], G2 = Lb[26];
      float4 H0 = Lb[28], H1 = Lb[29], H2 = Lb[30];
      for (int u = 0; u < SCH; u += 8) {
        SM_STEP(A0, A1, A2, 0)
        SM_STEP(B0, B1, B2, 1)
        SM_STEP(C0, C1, C2, 2)
        SM_STEP(D0, D1, D2, 3)
        SM_STEP(E0, E1, E2, 4)
        SM_STEP(F0, F1, F2, 5)
        SM_STEP(G0, G1, G2, 6)
        SM_STEP(H0, H1, H2, 7)
        if (((u + 7) & 63) == 63) {         // end of a 64-window group
          const int h = (c*SCH + u + 7) >> 6;
          qb[(size_t)(h*64 + l)*64 + n] = qs;
        }
      }
    }
    __syncthreads();
  }
}

// tv = y * 10^((mk - p)/20): exact 8-step reconstruction from boundary q.
// lanes = tracks -> fully coalesced y/tv rows.
__global__ __launch_bounds__(256) void k_mix1(float* __restrict__ ws) {
  const int n  = threadIdx.x & 63;
  const int kk = blockIdx.x*4 + (threadIdx.x >> 6);
  const float* cm = ws + OFF_COMP + n*32;
  const float aa = cm[0], ar = cm[1], kca = cm[2], kcr = cm[3];
  const float T = cm[4], hK = cm[5], cg1 = cm[6], cg2 = cm[7];
  const float mkK = cm[8], sK = cm[9];
  const float* __restrict__ yb  = ws + OFF_Y;
  float* __restrict__       tvb = ws + OFF_TV;
  float q = (kk > 0) ? ws[OFF_QB + (size_t)(kk-1)*64 + n] : 0.f;
  #pragma unroll
  for (int i = 0; i < 8; ++i) {
    float y = yb[(size_t)(kk*8 + i)*64 + n];
    float v   = fabsf(y) + 1e-8f;
    float xdb = 6.020599913279624f * __log2f(v);
    float d   = xdb - T;
    float dk  = d + hK;
    float gg  = (d > hK) ? (cg1*d) : (cg2*dk*dk);
    gg = (d < -hK) ? 0.f : gg;
    q = fmaxf(fmaf(aa, q, kca*gg), fmaf(ar, q, kcr*gg));
    float sc = exp2f(fmaf(-sK, q, mkK));
    tvb[(size_t)(kk*8 + i)*64 + n] = y * sc;
  }
}

// 16-track pan reduction -> out[b][2][S]
__global__ __launch_bounds__(256) void k_mix2(const float* __restrict__ ws,
                                              float* __restrict__ out) {
  const int b = threadIdx.x & 3;
  const int s = blockIdx.x*64 + (threadIdx.x >> 2);
  const float* __restrict__ tvb = ws + OFF_TV;
  const float2* __restrict__ wp = (const float2*)(ws + OFF_W);
  float accL = 0.f, accR = 0.f;
  const int n0 = b*16;
  #pragma unroll
  for (int t = 0; t < 16; ++t) {
    float tv = tvb[(size_t)s*64 + n0 + t];
    float2 w2 = wp[n0 + t];
    accL = fmaf(w2.x, tv, accL);
    accR = fmaf(w2.y, tv, accR);
  }
  out[(size_t)(b*2 + 0)*S_LEN + s] = accL;
  out[(size_t)(b*2 + 1)*S_LEN + s] = accR;
}

// ---------------------------------------------------------------------------
extern "C" void kernel_launch(void* const* d_in, const int* in_sizes, int n_in,
                              void* d_out, int out_size, void* d_ws, size_t ws_size,
                              hipStream_t stream) {
  const float* tracks = (const float*)d_in[0];
  const float* mp     = (const float*)d_in[1];
  float* ws  = (float*)d_ws;
  float* out = (float*)d_out;

  hipLaunchKernelGGL(k_setup,  dim3(1),    dim3(64),  0, stream, mp, ws);
  hipLaunchKernelGGL(k_matpow, dim3(64),   dim3(192), 0, stream, ws);
  hipLaunchKernelGGL(k_phase1, dim3(CCH),  dim3(64),  0, stream, tracks, ws);
  hipLaunchKernelGGL(k_scanz,  dim3(1),    dim3(64),  0, stream, ws);
  hipLaunchKernelGGL(k_phase3, dim3(CCH),  dim3(64),  0, stream, tracks, ws);
  hipLaunchKernelGGL(k_smooth, dim3(NTR),  dim3(256), 0, stream,
                     (const float4*)(ws + OFF_CI), ws + OFF_COMP, ws + OFF_QB);
  hipLaunchKernelGGL(k_mix1,   dim3(NSTEP/4),  dim3(256), 0, stream, ws);
  hipLaunchKernelGGL(k_mix2,   dim3(S_LEN/64), dim3(256), 0, stream, ws, out);
}

// Round 7
// 1029.453 us; speedup vs baseline: 3.0125x; 1.4220x over previous
//
#include <hip/hip_runtime.h>
#include <math.h>

// ---------------------------------------------------------------------------
// AdvancedMixConsole: 64 tracks x 131072 samples.
//   gain -> 6 biquads (chunk-parallel linear recurrence, 12-dim state)
//        -> compressor: parallel static gain; serial smoother as 8-sample
//           composed max-affine chain (9 slopes aa^j ar^(8-j)); one block per
//           track: wave0 = chain (uniform ds_read, named-reg depth-8 pipe,
//           __launch_bounds__(256,1) so the pipe stays in VGPRs),
//           waves1-3 = global->LDS producers (double-buffered chunks).
//        -> pan/mix (parallel, two-stage).
// ---------------------------------------------------------------------------

#define S_LEN 131072
#define NTR   64
#define CCH   256          // chunks (biquad phase)
#define LCH   512          // samples per chunk
#define NSTEP 16384        // 8-sample windows per track
#define WPC   64           // windows per biquad chunk
#define SCH   256          // k_smooth steps per LDS chunk
#define NCH   (NSTEP/SCH)  // 64 LDS chunks

typedef float v2f __attribute__((ext_vector_type(2)));

// ws offsets in floats (total ~106.5 MB)
#define OFF_Y    0ull              // [131072][64]      EQ output y, sample-major
#define OFF_CI   8388608ull        // [64][NSTEP][16]   composed intercepts I[0..8], 64B records
#define OFF_TV   8388608ull        // [131072][64]      tv = y*gain (ALIASES CI; used after k_smooth)
#define OFF_QB   25165824ull       // [NSTEP][64]       boundary q after each window
#define OFF_W    26214400ull       // [64][2]           cos/sin pan weights
#define OFF_COEF 26214528ull       // [64][32]          biquad coeffs
#define OFF_COMP 26216576ull       // [64][32]          compressor consts + 9 slopes
#define OFF_A    26218624ull       // [64][144]         cascade transition matrix
#define OFF_M    26227840ull       // [64][144]         A^LCH
#define OFF_F    26237056ull       // [64][CCH][12]     zero-init chunk finals
#define OFF_Z    26433664ull       // [64][CCH][12]     chunk init states

// ---------------------------------------------------------------------------
__global__ __launch_bounds__(64) void k_setup(const float* __restrict__ mp,
                                              float* __restrict__ ws) {
  int n = threadIdx.x;
  if (n >= NTR) return;
  const float* p = mp + n * 26;
  auto dn = [&](int i, double lo, double hi) { return (double)p[i] * (hi - lo) + lo; };

  double gain_db = dn(0, -24.0, 24.0);
  double glin = pow(10.0, gain_db / 20.0);
  const double nyq = 21050.0;  // 44100//2 - 1000

  double fg[6] = {dn(1,-24,24), dn(4,-24,24), dn(7,-24,24), dn(10,-24,24), dn(13,-24,24), dn(16,-24,24)};
  double ff[6] = {dn(2,20,2000), dn(5,80,2000), dn(8,2000,8000), dn(11,8000,12000), dn(14,12000,nyq), dn(17,6000,nyq)};
  double fq[6] = {dn(3,0.1,5), dn(6,0.1,5), dn(9,0.1,5), dn(12,0.1,5), dn(15,0.1,5), dn(18,0.1,5)};

  double B0[6], B1[6], B2[6], A1[6], A2[6];
  for (int k = 0; k < 6; k++) {
    double A  = pow(10.0, fg[k] / 40.0);
    double w0 = 2.0 * M_PI * ff[k] / 44100.0;
    double cw = cos(w0), sw = sin(w0);
    double al = sw / (2.0 * fq[k]);
    double sA = sqrt(A);
    double b0, b1, b2, a0, a1, a2;
    if (k == 0) {           // low shelf
      b0 = A*((A+1)-(A-1)*cw + 2*sA*al);
      b1 = 2*A*((A-1)-(A+1)*cw);
      b2 = A*((A+1)-(A-1)*cw - 2*sA*al);
      a0 = (A+1)+(A-1)*cw + 2*sA*al;
      a1 = -2*((A-1)+(A+1)*cw);
      a2 = (A+1)+(A-1)*cw - 2*sA*al;
    } else if (k == 5) {    // high shelf
      b0 = A*((A+1)+(A-1)*cw + 2*sA*al);
      b1 = -2*A*((A-1)+(A+1)*cw);
      b2 = A*((A+1)+(A-1)*cw - 2*sA*al);
      a0 = (A+1)-(A-1)*cw + 2*sA*al;
      a1 = 2*((A-1)-(A+1)*cw);
      a2 = (A+1)-(A-1)*cw - 2*sA*al;
    } else {                // peak
      b0 = 1 + al*A; b1 = -2*cw; b2 = 1 - al*A;
      a0 = 1 + al/A; a1 = -2*cw; a2 = 1 - al/A;
    }
    B0[k] = b0/a0; B1[k] = b1/a0; B2[k] = b2/a0; A1[k] = a1/a0; A2[k] = a2/a0;
  }
  // fold input gain into stage-0 numerator
  B0[0] *= glin; B1[0] *= glin; B2[0] *= glin;

  float* cf = ws + OFF_COEF + n * 32;
  for (int k = 0; k < 6; k++) {
    cf[k*5+0] = (float)B0[k]; cf[k*5+1] = (float)B1[k]; cf[k*5+2] = (float)B2[k];
    cf[k*5+3] = (float)A1[k]; cf[k*5+4] = (float)A2[k];
  }

  // compressor + pan constants
  double T = dn(19,-60,0), R = dn(20,1,10), atk = dn(21,1,1000), rel = dn(22,1,1000);
  double Kn = dn(23,3,24), mk = dn(24,0,24);
  double a_a = exp(-1.0 / (44100.0 * atk * 0.001));
  double a_r = exp(-1.0 / (44100.0 * rel * 0.001));
  double s   = (a_a < a_r) ? 1.0 : -1.0;     // q = s*p makes the recurrence pure-max
  double kca = s * (1.0 - a_a), kcr = s * (1.0 - a_r);
  double invR = 1.0 / R;
  const double K10 = 0.16609640474436813;    // log2(10)/20
  double theta = (double)p[25] * (M_PI / 2.0);

  float* cm = ws + OFF_COMP + n * 32;
  cm[0] = (float)a_a;  cm[1] = (float)a_r;  cm[2] = (float)kca; cm[3] = (float)kcr;
  cm[4] = (float)T;    cm[5] = (float)(Kn * 0.5);
  cm[6] = (float)(1.0 - invR);
  cm[7] = (float)((1.0 - invR) / (2.0 * Kn));
  cm[8] = (float)(mk * K10);   cm[9] = (float)(s * K10);
  cm[10] = (float)cos(theta);  cm[11] = (float)sin(theta);
  // 9 composed slopes aa^j * ar^(8-j), j = 0..8 (double-precision products)
  for (int j = 0; j <= 8; j++)
    cm[16+j] = (float)(pow(a_a, (double)j) * pow(a_r, (double)(8-j)));

  float* wp = ws + OFF_W + n*2;
  wp[0] = (float)cos(theta); wp[1] = (float)sin(theta);

  // homogeneous (x=0) cascade transition matrix, state = [s1_1,s2_1,...,s1_6,s2_6]
  double Am[12][12], yv[12], ny[12];
  for (int r = 0; r < 12; r++) { yv[r] = 0; for (int c = 0; c < 12; c++) Am[r][c] = 0; }
  for (int k = 0; k < 6; k++) {
    for (int c = 0; c < 12; c++) ny[c] = B0[k] * yv[c];
    ny[2*k] += 1.0;                                  // y_k = b0*y_{k-1} + s1_k
    for (int c = 0; c < 12; c++) Am[2*k][c]   = B1[k]*yv[c] - A1[k]*ny[c];
    Am[2*k][2*k+1] += 1.0;                           // + s2_k
    for (int c = 0; c < 12; c++) Am[2*k+1][c] = B2[k]*yv[c] - A2[k]*ny[c];
    for (int c = 0; c < 12; c++) yv[c] = ny[c];
  }
  float* Aw = ws + OFF_A + n * 144;
  for (int r = 0; r < 12; r++)
    for (int c = 0; c < 12; c++) Aw[r*12+c] = (float)Am[r][c];
}

// ---------------------------------------------------------------------------
__global__ __launch_bounds__(192) void k_matpow(float* __restrict__ ws) {
  __shared__ float As[144];
  int n = blockIdx.x, t = threadIdx.x;
  int r = t / 12, c = t % 12;
  if (t < 144) As[t] = ws[OFF_A + (size_t)n*144 + t];
  __syncthreads();
  for (int it = 0; it < 9; ++it) {   // A^(2^9) = A^LCH (LCH=512)
    float acc = 0.f;
    if (t < 144) {
      #pragma unroll
      for (int k = 0; k < 12; k++) acc += As[r*12+k] * As[k*12+c];
    }
    __syncthreads();
    if (t < 144) As[t] = acc;
    __syncthreads();
  }
  if (t < 144) ws[OFF_M + (size_t)n*144 + t] = As[t];
}

// ---------------------------------------------------------------------------
__device__ __forceinline__ void load_coefs(const float* cf, float* b0, v2f* bb, v2f* naa) {
  #pragma unroll
  for (int k = 0; k < 6; k++) {
    b0[k]  = cf[k*5+0];
    bb[k]  = (v2f){cf[k*5+1], cf[k*5+2]};
    naa[k] = (v2f){-cf[k*5+3], -cf[k*5+4]};
  }
}

__device__ __forceinline__ float cascade_step(float x, float* b0, v2f* bb, v2f* naa, v2f* st) {
  #pragma unroll
  for (int k = 0; k < 6; k++) {
    float y  = fmaf(b0[k], x, st[k].x);
    v2f upd  = __builtin_elementwise_fma(bb[k], (v2f){x, x}, (v2f){st[k].y, 0.f});
    st[k]    = __builtin_elementwise_fma(naa[k], (v2f){y, y}, upd);
    x = y;
  }
  return x;
}

// phase 1: zero-init chunk finals
__global__ __launch_bounds__(64) void k_phase1(const float* __restrict__ tracks,
                                               float* __restrict__ ws) {
  int j = blockIdx.x, n = threadIdx.x;
  float b0[6]; v2f bb[6], naa[6];
  load_coefs(ws + OFF_COEF + n*32, b0, bb, naa);
  v2f st[6];
  #pragma unroll
  for (int k = 0; k < 6; k++) st[k] = (v2f){0.f, 0.f};
  const float4* xp = (const float4*)(tracks + (size_t)n*S_LEN + (size_t)j*LCH);
  for (int i4 = 0; i4 < LCH/4; ++i4) {
    float4 xq = xp[i4];
    float xs[4] = {xq.x, xq.y, xq.z, xq.w};
    #pragma unroll
    for (int u = 0; u < 4; u++) (void)cascade_step(xs[u], b0, bb, naa, st);
  }
  float* f = ws + OFF_F + (size_t)n*(CCH*12) + (size_t)j*12;
  #pragma unroll
  for (int k = 0; k < 6; k++) { f[2*k] = st[k].x; f[2*k+1] = st[k].y; }
}

// serial scan of chunk-boundary states: z_{j+1} = M z_j + f_j
__global__ __launch_bounds__(64) void k_scanz(float* __restrict__ ws) {
  int n = threadIdx.x;
  float M[144];
  #pragma unroll
  for (int i = 0; i < 144; i++) M[i] = ws[OFF_M + (size_t)n*144 + i];
  float z[12];
  #pragma unroll
  for (int r = 0; r < 12; r++) z[r] = 0.f;
  const float* fb = ws + OFF_F + (size_t)n*(CCH*12);
  float*       zb = ws + OFF_Z + (size_t)n*(CCH*12);
  for (int j = 0; j < CCH; j++) {
    #pragma unroll
    for (int r = 0; r < 12; r++) zb[j*12+r] = z[r];
    float nz[12];
    #pragma unroll
    for (int r = 0; r < 12; r++) {
      float acc = fb[j*12+r];
      #pragma unroll
      for (int c = 0; c < 12; c++) acc = fmaf(M[r*12+c], z[c], acc);
      nz[r] = acc;
    }
    #pragma unroll
    for (int r = 0; r < 12; r++) z[r] = nz[r];
  }
}

// phase 3: correct-init EQ; per-sample static gain; per-8-sample-window
// composed max-affine intercepts I[0..8], written as 64B records
// [track][step][16] so k_smooth streams them with uniform loads.
__global__ __launch_bounds__(64) void k_phase3(const float* __restrict__ tracks,
                                               float* __restrict__ ws) {
  int j = blockIdx.x, n = threadIdx.x;
  float b0[6]; v2f bb[6], naa[6];
  load_coefs(ws + OFF_COEF + n*32, b0, bb, naa);
  const float* cm = ws + OFF_COMP + n*32;
  float a_a = cm[0], a_r = cm[1], kca = cm[2], kcr = cm[3];
  float T = cm[4], hK = cm[5], cg1 = cm[6], cg2 = cm[7];
  v2f st[6];
  const float* zp = ws + OFF_Z + (size_t)n*(CCH*12) + (size_t)j*12;
  #pragma unroll
  for (int k = 0; k < 6; k++) st[k] = (v2f){zp[2*k], zp[2*k+1]};

  const float4* xp = (const float4*)(tracks + (size_t)n*S_LEN + (size_t)j*LCH);
  float* yb = ws + OFF_Y + (size_t)j*LCH*64 + n;                    // [sample][track]
  float* cw = ws + OFF_CI + ((size_t)n*NSTEP + (size_t)j*WPC)*16;   // [track][step][16]

  for (int w = 0; w < WPC; ++w) {
    float I[9];
    I[0] = 0.f;
    #pragma unroll
    for (int jj = 1; jj < 9; ++jj) I[jj] = -1e30f;
    #pragma unroll
    for (int i4 = 0; i4 < 2; ++i4) {
      float4 xq = xp[w*2 + i4];
      float xs[4] = {xq.x, xq.y, xq.z, xq.w};
      #pragma unroll
      for (int u = 0; u < 4; ++u) {
        const int i = i4*4 + u;
        float y = cascade_step(xs[u], b0, bb, naa, st);
        yb[(w*8 + i)*64] = y;
        float v   = fabsf(y) + 1e-8f;
        float xdb = 6.020599913279624f * __log2f(v);
        float d   = xdb - T;
        float dk  = d + hK;
        float gg  = (d > hK) ? (cg1*d) : (cg2*dk*dk);
        gg = (d < -hK) ? 0.f : gg;
        float ca = kca*gg, cr = kcr*gg;
        // compose one sample into the window map (descending j, in place)
        #pragma unroll
        for (int jj = 8; jj >= 0; --jj) {
          if (jj <= i+1) {
            float up = (jj > 0) ? fmaf(a_a, I[jj-1], ca) : -1e30f;
            I[jj] = fmaxf(up, fmaf(a_r, I[jj], cr));
          }
        }
      }
    }
    float4* cq = (float4*)(cw + (size_t)w*16);
    cq[0] = make_float4(I[0], I[1], I[2], I[3]);
    cq[1] = make_float4(I[4], I[5], I[6], I[7]);
    cq[2] = make_float4(I[8], 0.f, 0.f, 0.f);
    cq[3] = make_float4(0.f, 0.f, 0.f, 0.f);   // complete the 64B line
  }
}

// ---------------------------------------------------------------------------
// serial max-affine smoother. One 256-thread block per track:
//   wave 0  = chain consumer: uniform-address ds_read broadcast, depth-8
//             pipeline of NAMED float4 locals. __launch_bounds__(256,1)
//             gives a 512-VGPR budget so the pipe is NOT sunk back to LDS.
//   waves 1-3 = producers: stream CI global->LDS, double-buffered chunks.
#define SM_CORE(Ra, Rb, Rc, SL)                                              \
    float t0 = fmaf(S0, q, Ra.x), t1 = fmaf(S1, q, Ra.y);                    \
    float t2 = fmaf(S2, q, Ra.z), t3 = fmaf(S3, q, Ra.w);                    \
    float t4 = fmaf(S4, q, Rb.x), t5 = fmaf(S5, q, Rb.y);                    \
    float t6 = fmaf(S6, q, Rb.z), t7 = fmaf(S7, q, Rb.w);                    \
    float t8 = fmaf(S8, q, Rc.x);                                            \
    float m0 = fmaxf(fmaxf(t0, t1), t2);                                     \
    float m1 = fmaxf(fmaxf(t3, t4), t5);                                     \
    float m2 = fmaxf(fmaxf(t6, t7), t8);                                     \
    q = fmaxf(fmaxf(m0, m1), m2);                                            \
    qs = (l == ((u + SL) & 63)) ? q : qs;

#define SM_STEP_R(Ra, Rb, Rc, SL)                                            \
  {                                                                          \
    SM_CORE(Ra, Rb, Rc, SL)                                                  \
    Ra = Lb[(u + SL + 8)*4 + 0];                                             \
    Rb = Lb[(u + SL + 8)*4 + 1];                                             \
    Rc = Lb[(u + SL + 8)*4 + 2];                                             \
  }

#define SM_STEP_N(Ra, Rb, Rc, SL)                                            \
  { SM_CORE(Ra, Rb, Rc, SL) }

__global__ __launch_bounds__(256, 1) void k_smooth(const float4* __restrict__ cp,
                                                   const float* __restrict__ cmv,
                                                   float* __restrict__ qb) {
  __shared__ float4 buf[2][SCH*4];          // 2 x 16KB
  const int n = blockIdx.x;
  const int tid = threadIdx.x;
  const int wave = tid >> 6, l = tid & 63;
  const float4* __restrict__ base = cp + (size_t)n * NSTEP * 4;

  // preload chunk 0 (all threads)
  for (int i = tid; i < SCH*4; i += 256) buf[0][i] = base[i];
  __syncthreads();

  const float* cm = cmv + n*32;
  const float S0 = cm[16], S1 = cm[17], S2 = cm[18], S3 = cm[19], S4 = cm[20];
  const float S5 = cm[21], S6 = cm[22], S7 = cm[23], S8 = cm[24];

  float q = 0.f, qs = 0.f;
  for (int c = 0; c < NCH; ++c) {
    if (wave != 0) {
      if (c + 1 < NCH) {
        const float4* src = base + (size_t)(c+1)*SCH*4;
        float4* dst = &buf[(c+1) & 1][0];
        for (int i = tid - 64; i < SCH*4; i += 192) dst[i] = src[i];
      }
    } else {
      const float4* Lb = &buf[c & 1][0];
      // prologue: steps 0..7 of this chunk into named regs
      float4 A0 = Lb[0],  A1 = Lb[1],  A2 = Lb[2];
      float4 B0 = Lb[4],  B1 = Lb[5],  B2 = Lb[6];
      float4 C0 = Lb[8],  C1 = Lb[9],  C2 = Lb[10];
      float4 D0 = Lb[12], D1 = Lb[13], D2 = Lb[14];
      float4 E0 = Lb[16], E1 = Lb[17], E2 = Lb[18];
      float4 F0 = Lb[20], F1 = Lb[21], F2 = Lb[22];
      float4 G0 = Lb[24], G1 = Lb[25], G2 = Lb[26];
      float4 H0 = Lb[28], H1 = Lb[29], H2 = Lb[30];
      // steady loop: unconditional refill 8 steps ahead (u < SCH-8)
      for (int u = 0; u < SCH - 8; u += 8) {
        SM_STEP_R(A0, A1, A2, 0)
        SM_STEP_R(B0, B1, B2, 1)
        SM_STEP_R(C0, C1, C2, 2)
        SM_STEP_R(D0, D1, D2, 3)
        SM_STEP_R(E0, E1, E2, 4)
        SM_STEP_R(F0, F1, F2, 5)
        SM_STEP_R(G0, G1, G2, 6)
        SM_STEP_R(H0, H1, H2, 7)
        if (((u + 7) & 63) == 63) {         // end of a 64-window group
          const int h = (c*SCH + u + 7) >> 6;
          qb[(size_t)(h*64 + l)*64 + n] = qs;
        }
      }
      // tail: last 8 steps of the chunk, no refill
      {
        const int u = SCH - 8;
        SM_STEP_N(A0, A1, A2, 0)
        SM_STEP_N(B0, B1, B2, 1)
        SM_STEP_N(C0, C1, C2, 2)
        SM_STEP_N(D0, D1, D2, 3)
        SM_STEP_N(E0, E1, E2, 4)
        SM_STEP_N(F0, F1, F2, 5)
        SM_STEP_N(G0, G1, G2, 6)
        SM_STEP_N(H0, H1, H2, 7)
        const int h = (c*SCH + SCH - 1) >> 6;
        qb[(size_t)(h*64 + l)*64 + n] = qs;
      }
    }
    __syncthreads();
  }
}

// tv = y * 10^((mk - p)/20): exact 8-step reconstruction from boundary q.
// lanes = tracks -> fully coalesced y/tv rows.
__global__ __launch_bounds__(256) void k_mix1(float* __restrict__ ws) {
  const int n  = threadIdx.x & 63;
  const int kk = blockIdx.x*4 + (threadIdx.x >> 6);
  const float* cm = ws + OFF_COMP + n*32;
  const float aa = cm[0], ar = cm[1], kca = cm[2], kcr = cm[3];
  const float T = cm[4], hK = cm[5], cg1 = cm[6], cg2 = cm[7];
  const float mkK = cm[8], sK = cm[9];
  const float* __restrict__ yb  = ws + OFF_Y;
  float* __restrict__       tvb = ws + OFF_TV;
  float q = (kk > 0) ? ws[OFF_QB + (size_t)(kk-1)*64 + n] : 0.f;
  #pragma unroll
  for (int i = 0; i < 8; ++i) {
    float y = yb[(size_t)(kk*8 + i)*64 + n];
    float v   = fabsf(y) + 1e-8f;
    float xdb = 6.020599913279624f * __log2f(v);
    float d   = xdb - T;
    float dk  = d + hK;
    float gg  = (d > hK) ? (cg1*d) : (cg2*dk*dk);
    gg = (d < -hK) ? 0.f : gg;
    q = fmaxf(fmaf(aa, q, kca*gg), fmaf(ar, q, kcr*gg));
    float sc = exp2f(fmaf(-sK, q, mkK));
    tvb[(size_t)(kk*8 + i)*64 + n] = y * sc;
  }
}

// 16-track pan reduction -> out[b][2][S]
__global__ __launch_bounds__(256) void k_mix2(const float* __restrict__ ws,
                                              float* __restrict__ out) {
  const int b = threadIdx.x & 3;
  const int s = blockIdx.x*64 + (threadIdx.x >> 2);
  const float* __restrict__ tvb = ws + OFF_TV;
  const float2* __restrict__ wp = (const float2*)(ws + OFF_W);
  float accL = 0.f, accR = 0.f;
  const int n0 = b*16;
  #pragma unroll
  for (int t = 0; t < 16; ++t) {
    float tv = tvb[(size_t)s*64 + n0 + t];
    float2 w2 = wp[n0 + t];
    accL = fmaf(w2.x, tv, accL);
    accR = fmaf(w2.y, tv, accR);
  }
  out[(size_t)(b*2 + 0)*S_LEN + s] = accL;
  out[(size_t)(b*2 + 1)*S_LEN + s] = accR;
}

// ---------------------------------------------------------------------------
extern "C" void kernel_launch(void* const* d_in, const int* in_sizes, int n_in,
                              void* d_out, int out_size, void* d_ws, size_t ws_size,
                              hipStream_t stream) {
  const float* tracks = (const float*)d_in[0];
  const float* mp     = (const float*)d_in[1];
  float* ws  = (float*)d_ws;
  float* out = (float*)d_out;

  hipLaunchKernelGGL(k_setup,  dim3(1),    dim3(64),  0, stream, mp, ws);
  hipLaunchKernelGGL(k_matpow, dim3(64),   dim3(192), 0, stream, ws);
  hipLaunchKernelGGL(k_phase1, dim3(CCH),  dim3(64),  0, stream, tracks, ws);
  hipLaunchKernelGGL(k_scanz,  dim3(1),    dim3(64),  0, stream, ws);
  hipLaunchKernelGGL(k_phase3, dim3(CCH),  dim3(64),  0, stream, tracks, ws);
  hipLaunchKernelGGL(k_smooth, dim3(NTR),  dim3(256), 0, stream,
                     (const float4*)(ws + OFF_CI), ws + OFF_COMP, ws + OFF_QB);
  hipLaunchKernelGGL(k_mix1,   dim3(NSTEP/4),  dim3(256), 0, stream, ws);
  hipLaunchKernelGGL(k_mix2,   dim3(S_LEN/64), dim3(256), 0, stream, ws, out);
}

// Round 8
// 962.943 us; speedup vs baseline: 3.2206x; 1.0691x over previous
//
#include <hip/hip_runtime.h>
#include <math.h>

// ---------------------------------------------------------------------------
// AdvancedMixConsole: 64 tracks x 131072 samples.
//   gain -> 6 biquads (chunk-parallel linear recurrence, 12-dim state)
//        -> compressor: parallel static gain; serial smoother as 16-sample
//           composed max-affine chain (17 slopes aa^j ar^(16-j)); one block
//           per track: wave0 = chain (uniform ds_read, 4-step double-buffered
//           named-reg pipe fenced with sched_barrier), waves1-3 = LDS producers.
//        -> pan/mix (parallel, two-stage).
// ---------------------------------------------------------------------------

#define S_LEN 131072
#define NTR   64
#define CCH   256          // chunks (biquad phase)
#define LCH   512          // samples per chunk
#define SMW   16           // smoother window
#define NST2  8192         // 16-sample windows per track
#define WPC2  32           // windows per biquad chunk
#define SCH2  128          // k_smooth steps per LDS chunk
#define NCH2  (NST2/SCH2)  // 64 LDS chunks
#define RECQ  5            // float4s per step record (17 slopes + pad)

typedef float v2f __attribute__((ext_vector_type(2)));

// ws offsets in floats (total ~79.3 MB)
#define OFF_Y    0ull              // [131072][64]      EQ output y, sample-major
#define OFF_CI   8388608ull        // [64][NST2][20]    composed intercepts I[0..16]+pad
#define OFF_TV   8388608ull        // [131072][64]      tv = y*gain (ALIASES CI)
#define OFF_QB   18874368ull       // [NST2][64]        boundary q after each window
#define OFF_W    19398656ull       // [64][2]           cos/sin pan weights
#define OFF_COEF 19398784ull       // [64][32]          biquad coeffs
#define OFF_COMP 19400832ull       // [64][64]          compressor consts + 17 slopes
#define OFF_A    19404928ull       // [64][144]         cascade transition matrix
#define OFF_M    19414144ull       // [64][144]         A^LCH
#define OFF_F    19423360ull       // [64][CCH][12]     zero-init chunk finals
#define OFF_Z    19619968ull       // [64][CCH][12]     chunk init states

#if __has_builtin(__builtin_amdgcn_sched_barrier)
#define SCHED_FENCE() __builtin_amdgcn_sched_barrier(0)
#else
#define SCHED_FENCE() asm volatile("" ::: "memory")
#endif

// ---------------------------------------------------------------------------
__global__ __launch_bounds__(64) void k_setup(const float* __restrict__ mp,
                                              float* __restrict__ ws) {
  int n = threadIdx.x;
  if (n >= NTR) return;
  const float* p = mp + n * 26;
  auto dn = [&](int i, double lo, double hi) { return (double)p[i] * (hi - lo) + lo; };

  double gain_db = dn(0, -24.0, 24.0);
  double glin = pow(10.0, gain_db / 20.0);
  const double nyq = 21050.0;  // 44100//2 - 1000

  double fg[6] = {dn(1,-24,24), dn(4,-24,24), dn(7,-24,24), dn(10,-24,24), dn(13,-24,24), dn(16,-24,24)};
  double ff[6] = {dn(2,20,2000), dn(5,80,2000), dn(8,2000,8000), dn(11,8000,12000), dn(14,12000,nyq), dn(17,6000,nyq)};
  double fq[6] = {dn(3,0.1,5), dn(6,0.1,5), dn(9,0.1,5), dn(12,0.1,5), dn(15,0.1,5), dn(18,0.1,5)};

  double B0[6], B1[6], B2[6], A1[6], A2[6];
  for (int k = 0; k < 6; k++) {
    double A  = pow(10.0, fg[k] / 40.0);
    double w0 = 2.0 * M_PI * ff[k] / 44100.0;
    double cw = cos(w0), sw = sin(w0);
    double al = sw / (2.0 * fq[k]);
    double sA = sqrt(A);
    double b0, b1, b2, a0, a1, a2;
    if (k == 0) {           // low shelf
      b0 = A*((A+1)-(A-1)*cw + 2*sA*al);
      b1 = 2*A*((A-1)-(A+1)*cw);
      b2 = A*((A+1)-(A-1)*cw - 2*sA*al);
      a0 = (A+1)+(A-1)*cw + 2*sA*al;
      a1 = -2*((A-1)+(A+1)*cw);
      a2 = (A+1)+(A-1)*cw - 2*sA*al;
    } else if (k == 5) {    // high shelf
      b0 = A*((A+1)+(A-1)*cw + 2*sA*al);
      b1 = -2*A*((A-1)+(A+1)*cw);
      b2 = A*((A+1)+(A-1)*cw - 2*sA*al);
      a0 = (A+1)-(A-1)*cw + 2*sA*al;
      a1 = 2*((A-1)-(A+1)*cw);
      a2 = (A+1)-(A-1)*cw - 2*sA*al;
    } else {                // peak
      b0 = 1 + al*A; b1 = -2*cw; b2 = 1 - al*A;
      a0 = 1 + al/A; a1 = -2*cw; a2 = 1 - al/A;
    }
    B0[k] = b0/a0; B1[k] = b1/a0; B2[k] = b2/a0; A1[k] = a1/a0; A2[k] = a2/a0;
  }
  // fold input gain into stage-0 numerator
  B0[0] *= glin; B1[0] *= glin; B2[0] *= glin;

  float* cf = ws + OFF_COEF + n * 32;
  for (int k = 0; k < 6; k++) {
    cf[k*5+0] = (float)B0[k]; cf[k*5+1] = (float)B1[k]; cf[k*5+2] = (float)B2[k];
    cf[k*5+3] = (float)A1[k]; cf[k*5+4] = (float)A2[k];
  }

  // compressor + pan constants
  double T = dn(19,-60,0), R = dn(20,1,10), atk = dn(21,1,1000), rel = dn(22,1,1000);
  double Kn = dn(23,3,24), mk = dn(24,0,24);
  double a_a = exp(-1.0 / (44100.0 * atk * 0.001));
  double a_r = exp(-1.0 / (44100.0 * rel * 0.001));
  double s   = (a_a < a_r) ? 1.0 : -1.0;     // q = s*p makes the recurrence pure-max
  double kca = s * (1.0 - a_a), kcr = s * (1.0 - a_r);
  double invR = 1.0 / R;
  const double K10 = 0.16609640474436813;    // log2(10)/20
  double theta = (double)p[25] * (M_PI / 2.0);

  float* cm = ws + OFF_COMP + n * 64;
  cm[0] = (float)a_a;  cm[1] = (float)a_r;  cm[2] = (float)kca; cm[3] = (float)kcr;
  cm[4] = (float)T;    cm[5] = (float)(Kn * 0.5);
  cm[6] = (float)(1.0 - invR);
  cm[7] = (float)((1.0 - invR) / (2.0 * Kn));
  cm[8] = (float)(mk * K10);   cm[9] = (float)(s * K10);
  cm[10] = (float)cos(theta);  cm[11] = (float)sin(theta);
  // 17 composed slopes aa^j * ar^(16-j), j = 0..16
  for (int j = 0; j <= 16; j++)
    cm[16+j] = (float)(pow(a_a, (double)j) * pow(a_r, (double)(16-j)));

  float* wp = ws + OFF_W + n*2;
  wp[0] = (float)cos(theta); wp[1] = (float)sin(theta);

  // homogeneous (x=0) cascade transition matrix, state = [s1_1,s2_1,...,s1_6,s2_6]
  double Am[12][12], yv[12], ny[12];
  for (int r = 0; r < 12; r++) { yv[r] = 0; for (int c = 0; c < 12; c++) Am[r][c] = 0; }
  for (int k = 0; k < 6; k++) {
    for (int c = 0; c < 12; c++) ny[c] = B0[k] * yv[c];
    ny[2*k] += 1.0;                                  // y_k = b0*y_{k-1} + s1_k
    for (int c = 0; c < 12; c++) Am[2*k][c]   = B1[k]*yv[c] - A1[k]*ny[c];
    Am[2*k][2*k+1] += 1.0;                           // + s2_k
    for (int c = 0; c < 12; c++) Am[2*k+1][c] = B2[k]*yv[c] - A2[k]*ny[c];
    for (int c = 0; c < 12; c++) yv[c] = ny[c];
  }
  float* Aw = ws + OFF_A + n * 144;
  for (int r = 0; r < 12; r++)
    for (int c = 0; c < 12; c++) Aw[r*12+c] = (float)Am[r][c];
}

// ---------------------------------------------------------------------------
__global__ __launch_bounds__(192) void k_matpow(float* __restrict__ ws) {
  __shared__ float As[144];
  int n = blockIdx.x, t = threadIdx.x;
  int r = t / 12, c = t % 12;
  if (t < 144) As[t] = ws[OFF_A + (size_t)n*144 + t];
  __syncthreads();
  for (int it = 0; it < 9; ++it) {   // A^(2^9) = A^LCH (LCH=512)
    float acc = 0.f;
    if (t < 144) {
      #pragma unroll
      for (int k = 0; k < 12; k++) acc += As[r*12+k] * As[k*12+c];
    }
    __syncthreads();
    if (t < 144) As[t] = acc;
    __syncthreads();
  }
  if (t < 144) ws[OFF_M + (size_t)n*144 + t] = As[t];
}

// ---------------------------------------------------------------------------
__device__ __forceinline__ void load_coefs(const float* cf, float* b0, v2f* bb, v2f* naa) {
  #pragma unroll
  for (int k = 0; k < 6; k++) {
    b0[k]  = cf[k*5+0];
    bb[k]  = (v2f){cf[k*5+1], cf[k*5+2]};
    naa[k] = (v2f){-cf[k*5+3], -cf[k*5+4]};
  }
}

__device__ __forceinline__ float cascade_step(float x, float* b0, v2f* bb, v2f* naa, v2f* st) {
  #pragma unroll
  for (int k = 0; k < 6; k++) {
    float y  = fmaf(b0[k], x, st[k].x);
    v2f upd  = __builtin_elementwise_fma(bb[k], (v2f){x, x}, (v2f){st[k].y, 0.f});
    st[k]    = __builtin_elementwise_fma(naa[k], (v2f){y, y}, upd);
    x = y;
  }
  return x;
}

// phase 1: zero-init chunk finals
__global__ __launch_bounds__(64) void k_phase1(const float* __restrict__ tracks,
                                               float* __restrict__ ws) {
  int j = blockIdx.x, n = threadIdx.x;
  float b0[6]; v2f bb[6], naa[6];
  load_coefs(ws + OFF_COEF + n*32, b0, bb, naa);
  v2f st[6];
  #pragma unroll
  for (int k = 0; k < 6; k++) st[k] = (v2f){0.f, 0.f};
  const float4* xp = (const float4*)(tracks + (size_t)n*S_LEN + (size_t)j*LCH);
  for (int i4 = 0; i4 < LCH/4; ++i4) {
    float4 xq = xp[i4];
    float xs[4] = {xq.x, xq.y, xq.z, xq.w};
    #pragma unroll
    for (int u = 0; u < 4; u++) (void)cascade_step(xs[u], b0, bb, naa, st);
  }
  float* f = ws + OFF_F + (size_t)n*(CCH*12) + (size_t)j*12;
  #pragma unroll
  for (int k = 0; k < 6; k++) { f[2*k] = st[k].x; f[2*k+1] = st[k].y; }
}

// serial scan of chunk-boundary states: z_{j+1} = M z_j + f_j
__global__ __launch_bounds__(64) void k_scanz(float* __restrict__ ws) {
  int n = threadIdx.x;
  float M[144];
  #pragma unroll
  for (int i = 0; i < 144; i++) M[i] = ws[OFF_M + (size_t)n*144 + i];
  float z[12];
  #pragma unroll
  for (int r = 0; r < 12; r++) z[r] = 0.f;
  const float* fb = ws + OFF_F + (size_t)n*(CCH*12);
  float*       zb = ws + OFF_Z + (size_t)n*(CCH*12);
  for (int j = 0; j < CCH; j++) {
    #pragma unroll
    for (int r = 0; r < 12; r++) zb[j*12+r] = z[r];
    float nz[12];
    #pragma unroll
    for (int r = 0; r < 12; r++) {
      float acc = fb[j*12+r];
      #pragma unroll
      for (int c = 0; c < 12; c++) acc = fmaf(M[r*12+c], z[c], acc);
      nz[r] = acc;
    }
    #pragma unroll
    for (int r = 0; r < 12; r++) z[r] = nz[r];
  }
}

// phase 3: correct-init EQ; per-sample static gain; per-16-sample-window
// composed max-affine intercepts I[0..16] (I[j] = best path with j attacks),
// written as 80B records [track][step][20] for k_smooth's uniform loads.
__global__ __launch_bounds__(64) void k_phase3(const float* __restrict__ tracks,
                                               float* __restrict__ ws) {
  int j = blockIdx.x, n = threadIdx.x;
  float b0[6]; v2f bb[6], naa[6];
  load_coefs(ws + OFF_COEF + n*32, b0, bb, naa);
  const float* cm = ws + OFF_COMP + n*64;
  float a_a = cm[0], a_r = cm[1], kca = cm[2], kcr = cm[3];
  float T = cm[4], hK = cm[5], cg1 = cm[6], cg2 = cm[7];
  v2f st[6];
  const float* zp = ws + OFF_Z + (size_t)n*(CCH*12) + (size_t)j*12;
  #pragma unroll
  for (int k = 0; k < 6; k++) st[k] = (v2f){zp[2*k], zp[2*k+1]};

  const float4* xp = (const float4*)(tracks + (size_t)n*S_LEN + (size_t)j*LCH);
  float* yb = ws + OFF_Y + (size_t)j*LCH*64 + n;                      // [sample][track]
  float* cw = ws + OFF_CI + ((size_t)n*NST2 + (size_t)j*WPC2)*20;     // [track][step][20]

  for (int w = 0; w < WPC2; ++w) {
    float I[17];
    I[0] = 0.f;
    #pragma unroll
    for (int jj = 1; jj < 17; ++jj) I[jj] = -1e30f;
    #pragma unroll
    for (int i4 = 0; i4 < 4; ++i4) {
      float4 xq = xp[w*4 + i4];
      float xs[4] = {xq.x, xq.y, xq.z, xq.w};
      #pragma unroll
      for (int u = 0; u < 4; ++u) {
        const int i = i4*4 + u;
        float y = cascade_step(xs[u], b0, bb, naa, st);
        yb[(w*16 + i)*64] = y;
        float v   = fabsf(y) + 1e-8f;
        float xdb = 6.020599913279624f * __log2f(v);
        float d   = xdb - T;
        float dk  = d + hK;
        float gg  = (d > hK) ? (cg1*d) : (cg2*dk*dk);
        gg = (d < -hK) ? 0.f : gg;
        float ca = kca*gg, cr = kcr*gg;
        // compose one sample into the window map (descending j, in place)
        #pragma unroll
        for (int jj = 16; jj >= 0; --jj) {
          if (jj <= i+1) {
            float up = (jj > 0) ? fmaf(a_a, I[jj-1], ca) : -1e30f;
            I[jj] = fmaxf(up, fmaf(a_r, I[jj], cr));
          }
        }
      }
    }
    float4* cq = (float4*)(cw + (size_t)w*20);
    cq[0] = make_float4(I[0],  I[1],  I[2],  I[3]);
    cq[1] = make_float4(I[4],  I[5],  I[6],  I[7]);
    cq[2] = make_float4(I[8],  I[9],  I[10], I[11]);
    cq[3] = make_float4(I[12], I[13], I[14], I[15]);
    cq[4] = make_float4(I[16], 0.f, 0.f, 0.f);
  }
}

// ---------------------------------------------------------------------------
// serial max-affine smoother. One 256-thread block per track:
//   wave 0  = chain: uniform ds_read, 4-step double-buffered named-reg pipe;
//             sched_barrier(0) pins loads BEFORE compute (LDS ops retire in
//             order, so current-group values are ready without extra waits).
//   waves 1-3 = producers: stream CI global->LDS, double-buffered chunks.
#define LOADSTEP(A,B,C,D,E, IDX)                                             \
  A = Lb[(IDX)*RECQ+0]; B = Lb[(IDX)*RECQ+1]; C = Lb[(IDX)*RECQ+2];          \
  D = Lb[(IDX)*RECQ+3]; E = Lb[(IDX)*RECQ+4];

#define EVAL_STEP(A,B,C,D,E, LCL)                                            \
  {                                                                          \
    float t0  = fmaf(S0,q,A.x),  t1  = fmaf(S1,q,A.y);                       \
    float t2  = fmaf(S2,q,A.z),  t3  = fmaf(S3,q,A.w);                       \
    float t4  = fmaf(S4,q,B.x),  t5  = fmaf(S5,q,B.y);                       \
    float t6  = fmaf(S6,q,B.z),  t7  = fmaf(S7,q,B.w);                       \
    float t8  = fmaf(S8,q,C.x),  t9  = fmaf(S9,q,C.y);                       \
    float t10 = fmaf(S10,q,C.z), t11 = fmaf(S11,q,C.w);                      \
    float t12 = fmaf(S12,q,D.x), t13 = fmaf(S13,q,D.y);                      \
    float t14 = fmaf(S14,q,D.z), t15 = fmaf(S15,q,D.w);                      \
    float t16 = fmaf(S16,q,E.x);                                             \
    float m0 = fmaxf(fmaxf(t0,t1),t2);                                       \
    float m1 = fmaxf(fmaxf(t3,t4),t5);                                       \
    float m2 = fmaxf(fmaxf(t6,t7),t8);                                       \
    float m3 = fmaxf(fmaxf(t9,t10),t11);                                     \
    float m4 = fmaxf(fmaxf(t12,t13),t14);                                    \
    float m5 = fmaxf(fmaxf(t15,t16),m0);                                     \
    float mm = fmaxf(fmaxf(m1,m2),m3);                                       \
    q = fmaxf(fmaxf(m4,m5),mm);                                              \
    qs = (l == ((LCL) & 63)) ? q : qs;                                       \
  }

__global__ __launch_bounds__(256, 1) void k_smooth(const float4* __restrict__ cp,
                                                   const float* __restrict__ cmv,
                                                   float* __restrict__ qb) {
  __shared__ float4 buf[2][SCH2*RECQ];      // 2 x 10KB
  const int n = blockIdx.x;
  const int tid = threadIdx.x;
  const int wave = tid >> 6, l = tid & 63;
  const float4* __restrict__ base = cp + (size_t)n * NST2 * RECQ;

  // preload chunk 0 (all threads)
  for (int i = tid; i < SCH2*RECQ; i += 256) buf[0][i] = base[i];
  __syncthreads();

  const float* cm = cmv + n*64;
  const float S0  = cm[16], S1  = cm[17], S2  = cm[18], S3  = cm[19];
  const float S4  = cm[20], S5  = cm[21], S6  = cm[22], S7  = cm[23];
  const float S8  = cm[24], S9  = cm[25], S10 = cm[26], S11 = cm[27];
  const float S12 = cm[28], S13 = cm[29], S14 = cm[30], S15 = cm[31];
  const float S16 = cm[32];

  float q = 0.f, qs = 0.f;
  for (int c2 = 0; c2 < NCH2; ++c2) {
    if (wave != 0) {
      if (c2 + 1 < NCH2) {
        const float4* src = base + (size_t)(c2+1)*SCH2*RECQ;
        float4* dst = &buf[(c2+1) & 1][0];
        for (int i = tid - 64; i < SCH2*RECQ; i += 192) dst[i] = src[i];
      }
    } else {
      const float4* Lb = &buf[c2 & 1][0];
      float4 p0a,p0b,p0c,p0d,p0e, p1a,p1b,p1c,p1d,p1e;
      float4 p2a,p2b,p2c,p2d,p2e, p3a,p3b,p3c,p3d,p3e;
      float4 n0a,n0b,n0c,n0d,n0e, n1a,n1b,n1c,n1d,n1e;
      float4 n2a,n2b,n2c,n2d,n2e, n3a,n3b,n3c,n3d,n3e;
      LOADSTEP(p0a,p0b,p0c,p0d,p0e, 0)
      LOADSTEP(p1a,p1b,p1c,p1d,p1e, 1)
      LOADSTEP(p2a,p2b,p2c,p2d,p2e, 2)
      LOADSTEP(p3a,p3b,p3c,p3d,p3e, 3)
      for (int g = 0; g < SCH2/4; g += 2) {
        const int w0 = c2*SCH2 + g*4;
        // prefetch group g+1 into N
        LOADSTEP(n0a,n0b,n0c,n0d,n0e, (g+1)*4+0)
        LOADSTEP(n1a,n1b,n1c,n1d,n1e, (g+1)*4+1)
        LOADSTEP(n2a,n2b,n2c,n2d,n2e, (g+1)*4+2)
        LOADSTEP(n3a,n3b,n3c,n3d,n3e, (g+1)*4+3)
        SCHED_FENCE();
        EVAL_STEP(p0a,p0b,p0c,p0d,p0e, w0+0)
        EVAL_STEP(p1a,p1b,p1c,p1d,p1e, w0+1)
        EVAL_STEP(p2a,p2b,p2c,p2d,p2e, w0+2)
        EVAL_STEP(p3a,p3b,p3c,p3d,p3e, w0+3)
        if (((w0+3) & 63) == 63)
          qb[(size_t)(((w0+3) >> 6)*64 + l)*64 + n] = qs;
        // prefetch group g+2 into P (clamped at chunk end; extra read harmless)
        {
          const int gp = (g+2 < SCH2/4) ? g+2 : SCH2/4-1;
          LOADSTEP(p0a,p0b,p0c,p0d,p0e, gp*4+0)
          LOADSTEP(p1a,p1b,p1c,p1d,p1e, gp*4+1)
          LOADSTEP(p2a,p2b,p2c,p2d,p2e, gp*4+2)
          LOADSTEP(p3a,p3b,p3c,p3d,p3e, gp*4+3)
        }
        SCHED_FENCE();
        EVAL_STEP(n0a,n0b,n0c,n0d,n0e, w0+4)
        EVAL_STEP(n1a,n1b,n1c,n1d,n1e, w0+5)
        EVAL_STEP(n2a,n2b,n2c,n2d,n2e, w0+6)
        EVAL_STEP(n3a,n3b,n3c,n3d,n3e, w0+7)
        if (((w0+7) & 63) == 63)
          qb[(size_t)(((w0+7) >> 6)*64 + l)*64 + n] = qs;
      }
    }
    __syncthreads();
  }
}

// tv = y * 10^((mk - p)/20): exact 16-step reconstruction from boundary q.
// lanes = tracks -> fully coalesced y/tv rows.
__global__ __launch_bounds__(256) void k_mix1(float* __restrict__ ws) {
  const int n  = threadIdx.x & 63;
  const int kk = blockIdx.x*4 + (threadIdx.x >> 6);
  const float* cm = ws + OFF_COMP + n*64;
  const float aa = cm[0], ar = cm[1], kca = cm[2], kcr = cm[3];
  const float T = cm[4], hK = cm[5], cg1 = cm[6], cg2 = cm[7];
  const float mkK = cm[8], sK = cm[9];
  const float* __restrict__ yb  = ws + OFF_Y;
  float* __restrict__       tvb = ws + OFF_TV;
  float q = (kk > 0) ? ws[OFF_QB + (size_t)(kk-1)*64 + n] : 0.f;
  #pragma unroll
  for (int i = 0; i < SMW; ++i) {
    float y = yb[(size_t)(kk*SMW + i)*64 + n];
    float v   = fabsf(y) + 1e-8f;
    float xdb = 6.020599913279624f * __log2f(v);
    float d   = xdb - T;
    float dk  = d + hK;
    float gg  = (d > hK) ? (cg1*d) : (cg2*dk*dk);
    gg = (d < -hK) ? 0.f : gg;
    q = fmaxf(fmaf(aa, q, kca*gg), fmaf(ar, q, kcr*gg));
    float sc = exp2f(fmaf(-sK, q, mkK));
    tvb[(size_t)(kk*SMW + i)*64 + n] = y * sc;
  }
}

// 16-track pan reduction -> out[b][2][S]
__global__ __launch_bounds__(256) void k_mix2(const float* __restrict__ ws,
                                              float* __restrict__ out) {
  const int b = threadIdx.x & 3;
  const int s = blockIdx.x*64 + (threadIdx.x >> 2);
  const float* __restrict__ tvb = ws + OFF_TV;
  const float2* __restrict__ wp = (const float2*)(ws + OFF_W);
  float accL = 0.f, accR = 0.f;
  const int n0 = b*16;
  #pragma unroll
  for (int t = 0; t < 16; ++t) {
    float tv = tvb[(size_t)s*64 + n0 + t];
    float2 w2 = wp[n0 + t];
    accL = fmaf(w2.x, tv, accL);
    accR = fmaf(w2.y, tv, accR);
  }
  out[(size_t)(b*2 + 0)*S_LEN + s] = accL;
  out[(size_t)(b*2 + 1)*S_LEN + s] = accR;
}

// ---------------------------------------------------------------------------
extern "C" void kernel_launch(void* const* d_in, const int* in_sizes, int n_in,
                              void* d_out, int out_size, void* d_ws, size_t ws_size,
                              hipStream_t stream) {
  const float* tracks = (const float*)d_in[0];
  const float* mp     = (const float*)d_in[1];
  float* ws  = (float*)d_ws;
  float* out = (float*)d_out;

  hipLaunchKernelGGL(k_setup,  dim3(1),    dim3(64),  0, stream, mp, ws);
  hipLaunchKernelGGL(k_matpow, dim3(64),   dim3(192), 0, stream, ws);
  hipLaunchKernelGGL(k_phase1, dim3(CCH),  dim3(64),  0, stream, tracks, ws);
  hipLaunchKernelGGL(k_scanz,  dim3(1),    dim3(64),  0, stream, ws);
  hipLaunchKernelGGL(k_phase3, dim3(CCH),  dim3(64),  0, stream, tracks, ws);
  hipLaunchKernelGGL(k_smooth, dim3(NTR),  dim3(256), 0, stream,
                     (const float4*)(ws + OFF_CI), ws + OFF_COMP, ws + OFF_QB);
  hipLaunchKernelGGL(k_mix1,   dim3(NST2/4),  dim3(256), 0, stream, ws);
  hipLaunchKernelGGL(k_mix2,   dim3(S_LEN/64), dim3(256), 0, stream, ws, out);
}